// Round 1
// baseline (18703.369 us; speedup 1.0000x reference)
//
#include <hip/hip_runtime.h>
#include <cmath>

#define NBLK 256
#define NTH  512
#define LDA  68

#define BATCH 512
#define TENC  256
#define INSZ  32
#define HID   256
#define PREDW 30

#define NTICKS 288

struct SParams {
  const float *input, *target;
  const float *eWih0, *eWhh0, *eBih0, *eBhh0;
  const float *eWih1, *eWhh1, *eBih1, *eBhh1;
  const float *dWih0, *dWhh0, *dBih0, *dBhh0;
  const float *dWih1, *dWhh1, *dBih1, *dBhh1;
  const float *fcw, *fcb;
  float *out;
  float *h0, *h1;     // each [2][BATCH][HID] double-buffered in ws
  unsigned *cnt;      // grid barrier counter in ws
};

__device__ __forceinline__ float sigf(float x) { return 1.0f / (1.0f + expf(-x)); }

__device__ __forceinline__ void grid_sync(unsigned* cnt, unsigned epoch) {
  __syncthreads();
  if (threadIdx.x == 0) {
    __threadfence();
    __hip_atomic_fetch_add(cnt, 1u, __ATOMIC_ACQ_REL, __HIP_MEMORY_SCOPE_AGENT);
    const unsigned tgt = (unsigned)NBLK * epoch;
    while (__hip_atomic_load(cnt, __ATOMIC_ACQUIRE, __HIP_MEMORY_SCOPE_AGENT) < tgt) {
      __builtin_amdgcn_s_sleep(2);
    }
    __threadfence();
  }
  __syncthreads();
}

// Accumulate acc[2][4] += A_tile[64 x Ksrc] * W_rows(gate-cols)^T for this thread's
// (2 rows, 4 gates of one hdim). A[r][k] = Asrc[(R0+r)*aStride + aOff + k].
// W gate-col cg (= g*16+jj) maps to W row g*256 + D0 + jj, row length Ksrc.
__device__ __forceinline__ void seg_accum(
    float acc[2][4],
    const float* __restrict__ Asrc, int aStride, int aOff,
    const float* __restrict__ Wsrc, int Ksrc,
    int R0, int D0, int tid, float* As, float* Ws)
{
  const int j  = tid & 15;
  const int rb = tid >> 4;
  for (int k0 = 0; k0 < Ksrc; k0 += 64) {
    const int KC = (Ksrc - k0 >= 64) ? 64 : (Ksrc - k0);   // 64 or 32
    const int nq = KC >> 2;                                 // 16 or 8
    const int sh = (nq == 16) ? 4 : 3;
    const int tot = 64 * nq;
    __syncthreads();
    for (int idx = tid; idx < tot; idx += NTH) {
      const int r = idx >> sh, qq = idx & (nq - 1);
      *(float4*)(As + r * LDA + 4 * qq) =
          *(const float4*)(Asrc + (size_t)(R0 + r) * aStride + aOff + k0 + 4 * qq);
    }
    for (int idx = tid; idx < tot; idx += NTH) {
      const int cg = idx >> sh, qq = idx & (nq - 1);
      const int wrow = ((cg >> 4) << 8) + D0 + (cg & 15);
      *(float4*)(Ws + cg * LDA + 4 * qq) =
          *(const float4*)(Wsrc + (size_t)wrow * Ksrc + k0 + 4 * qq);
    }
    __syncthreads();
    const float* pa0 = As + (rb * 2) * LDA;
    const float* pa1 = pa0 + LDA;
    const float* pw0 = Ws + j * LDA;
    const float* pw1 = Ws + (16 + j) * LDA;
    const float* pw2 = Ws + (32 + j) * LDA;
    const float* pw3 = Ws + (48 + j) * LDA;
    #pragma unroll 4
    for (int kk = 0; kk < KC; kk += 4) {
      float a0[4], a1[4], w0[4], w1[4], w2[4], w3[4];
      *(float4*)a0 = *(const float4*)(pa0 + kk);
      *(float4*)a1 = *(const float4*)(pa1 + kk);
      *(float4*)w0 = *(const float4*)(pw0 + kk);
      *(float4*)w1 = *(const float4*)(pw1 + kk);
      *(float4*)w2 = *(const float4*)(pw2 + kk);
      *(float4*)w3 = *(const float4*)(pw3 + kk);
      #pragma unroll
      for (int q = 0; q < 4; ++q) {
        acc[0][0] = fmaf(a0[q], w0[q], acc[0][0]);
        acc[0][1] = fmaf(a0[q], w1[q], acc[0][1]);
        acc[0][2] = fmaf(a0[q], w2[q], acc[0][2]);
        acc[0][3] = fmaf(a0[q], w3[q], acc[0][3]);
        acc[1][0] = fmaf(a1[q], w0[q], acc[1][0]);
        acc[1][1] = fmaf(a1[q], w1[q], acc[1][1]);
        acc[1][2] = fmaf(a1[q], w2[q], acc[1][2]);
        acc[1][3] = fmaf(a1[q], w3[q], acc[1][3]);
      }
    }
  }
}

__device__ __forceinline__ void upd_store(
    float acc[2][4], float c[2], float* hdst,
    int R0, int D0, int tid, bool dofc, float fcwj, float* out, int s)
{
  const int j  = tid & 15;
  const int r0 = R0 + (tid >> 4) * 2;
  #pragma unroll
  for (int i = 0; i < 2; ++i) {
    const float ig = sigf(acc[i][0]);
    const float fg = sigf(acc[i][1]);
    const float gg = tanhf(acc[i][2]);
    const float og = sigf(acc[i][3]);
    c[i] = fg * c[i] + ig * gg;
    const float h = og * tanhf(c[i]);
    hdst[(size_t)(r0 + i) * HID + D0 + j] = h;
    if (dofc) {
      float pp = h * fcwj;
      pp += __shfl_xor(pp, 1);
      pp += __shfl_xor(pp, 2);
      pp += __shfl_xor(pp, 4);
      pp += __shfl_xor(pp, 8);
      if (j == 0) atomicAdd(out + (r0 + i) * PREDW + s, pp);
    }
  }
}

__global__ __launch_bounds__(NTH) void seq2seq_kernel(SParams p)
{
  __shared__ __align__(16) float As[64 * LDA];
  __shared__ __align__(16) float Ws[64 * LDA];
  const int tid = threadIdx.x;
  const int bid = blockIdx.x;

  // XCD-aware role mapping: the 8 row-blocks sharing (layer, dtile) all get
  // bid ≡ same (mod 8) -> same XCD (assumes xcd = bid & 7) -> their W tile
  // stays resident in that XCD's L2 across all ticks.
  const int xcd   = bid & 7;
  const int hi    = bid >> 3;
  const int rtile = hi & 7;
  const int loc   = hi >> 3;            // 0..3
  const int q     = loc * 8 + xcd;      // 0..31 pair id
  const int layer = q >> 4;
  const int dtile = q & 15;
  const int R0 = rtile * 64;
  const int D0 = dtile * 16;
  const int j  = tid & 15;
  const int dim = D0 + j;

  const float *bi_e, *bh_e, *bi_d, *bh_d;
  if (layer == 0) { bi_e = p.eBih0; bh_e = p.eBhh0; bi_d = p.dBih0; bh_d = p.dBhh0; }
  else            { bi_e = p.eBih1; bh_e = p.eBhh1; bi_d = p.dBih1; bh_d = p.dBhh1; }
  float be[4], bd[4], wxd[4];
  #pragma unroll
  for (int g = 0; g < 4; ++g) {
    const int grow = g * 256 + dim;
    be[g]  = bi_e[grow] + bh_e[grow];
    bd[g]  = bi_d[grow] + bh_d[grow];
    wxd[g] = (layer == 0) ? p.dWih0[grow] : 0.0f;   // dec W_ih0 is [1024,1]
  }
  const float fcwj = p.fcw[dim];
  const float fcb0 = p.fcb[0];

  // init output to fc bias (d_out is poisoned before every launch)
  for (int idx = bid * NTH + tid; idx < BATCH * PREDW; idx += NBLK * NTH)
    p.out[idx] = fcb0;

  float c[2] = {0.0f, 0.0f};   // cell state lives in registers for the whole run
  unsigned epoch = 1;

  for (int tick = 0; tick < NTICKS; ++tick) {
    const int rp = tick & 1;
    const int wp = rp ^ 1;
    float* h0r = p.h0 + (size_t)rp * BATCH * HID;
    float* h0w = p.h0 + (size_t)wp * BATCH * HID;
    float* h1r = p.h1 + (size_t)rp * BATCH * HID;
    float* h1w = p.h1 + (size_t)wp * BATCH * HID;

    if (layer == 0) {
      if (tick < 256) {                       // encoder L0 step t=tick
        float acc[2][4];
        #pragma unroll
        for (int g = 0; g < 4; ++g) { acc[0][g] = be[g]; acc[1][g] = be[g]; }
        seg_accum(acc, p.input, TENC * INSZ, tick * INSZ, p.eWih0, INSZ, R0, D0, tid, As, Ws);
        seg_accum(acc, h0r, HID, 0, p.eWhh0, HID, R0, D0, tid, As, Ws);
        upd_store(acc, c, h0w, R0, D0, tid, false, 0.0f, p.out, 0);
      } else if (tick == 256) {               // parity carry h0
        const int r0 = R0 + (tid >> 4) * 2;
        h0w[(size_t)r0 * HID + dim]       = h0r[(size_t)r0 * HID + dim];
        h0w[(size_t)(r0 + 1) * HID + dim] = h0r[(size_t)(r0 + 1) * HID + dim];
      } else if (tick < 257 + PREDW) {        // decoder L0 step s
        const int s = tick - 257;
        const int r0 = R0 + (tid >> 4) * 2;
        const float x0 = p.target[r0 * PREDW + s];
        const float x1 = p.target[(r0 + 1) * PREDW + s];
        float acc[2][4];
        #pragma unroll
        for (int g = 0; g < 4; ++g) {
          acc[0][g] = bd[g] + x0 * wxd[g];
          acc[1][g] = bd[g] + x1 * wxd[g];
        }
        seg_accum(acc, h0r, HID, 0, p.dWhh0, HID, R0, D0, tid, As, Ws);
        upd_store(acc, c, h0w, R0, D0, tid, false, 0.0f, p.out, 0);
      }
    } else {
      if (tick >= 1 && tick <= 256) {         // encoder L1 step s=tick-1
        float acc[2][4];
        #pragma unroll
        for (int g = 0; g < 4; ++g) { acc[0][g] = be[g]; acc[1][g] = be[g]; }
        seg_accum(acc, h0r, HID, 0, p.eWih1, HID, R0, D0, tid, As, Ws);
        seg_accum(acc, h1r, HID, 0, p.eWhh1, HID, R0, D0, tid, As, Ws);
        upd_store(acc, c, h1w, R0, D0, tid, false, 0.0f, p.out, 0);
      } else if (tick == 257) {               // parity carry h1
        const int r0 = R0 + (tid >> 4) * 2;
        h1w[(size_t)r0 * HID + dim]       = h1r[(size_t)r0 * HID + dim];
        h1w[(size_t)(r0 + 1) * HID + dim] = h1r[(size_t)(r0 + 1) * HID + dim];
      } else if (tick >= 258) {               // decoder L1 step s=tick-258 (+fc)
        const int s = tick - 258;
        float acc[2][4];
        #pragma unroll
        for (int g = 0; g < 4; ++g) { acc[0][g] = bd[g]; acc[1][g] = bd[g]; }
        seg_accum(acc, h0r, HID, 0, p.dWih1, HID, R0, D0, tid, As, Ws);
        seg_accum(acc, h1r, HID, 0, p.dWhh1, HID, R0, D0, tid, As, Ws);
        upd_store(acc, c, h1w, R0, D0, tid, true, fcwj, p.out, s);
      }
    }
    grid_sync(p.cnt, epoch);
    ++epoch;
  }
}

extern "C" void kernel_launch(void* const* d_in, const int* in_sizes, int n_in,
                              void* d_out, int out_size, void* d_ws, size_t ws_size,
                              hipStream_t stream)
{
  SParams p;
  p.input = (const float*)d_in[0];
  p.target = (const float*)d_in[1];
  p.eWih0 = (const float*)d_in[2];  p.eWhh0 = (const float*)d_in[3];
  p.eBih0 = (const float*)d_in[4];  p.eBhh0 = (const float*)d_in[5];
  p.eWih1 = (const float*)d_in[6];  p.eWhh1 = (const float*)d_in[7];
  p.eBih1 = (const float*)d_in[8];  p.eBhh1 = (const float*)d_in[9];
  p.dWih0 = (const float*)d_in[10]; p.dWhh0 = (const float*)d_in[11];
  p.dBih0 = (const float*)d_in[12]; p.dBhh0 = (const float*)d_in[13];
  p.dWih1 = (const float*)d_in[14]; p.dWhh1 = (const float*)d_in[15];
  p.dBih1 = (const float*)d_in[16]; p.dBhh1 = (const float*)d_in[17];
  p.fcw = (const float*)d_in[18];   p.fcb = (const float*)d_in[19];
  p.out = (float*)d_out;

  float* ws = (float*)d_ws;
  p.h0 = ws;                                  // [2][512][256]
  p.h1 = ws + 2 * BATCH * HID;                // [2][512][256]
  p.cnt = (unsigned*)(ws + 4 * BATCH * HID);  // barrier counter

  // zero h buffers + barrier counter (ws is poisoned before every launch)
  hipMemsetAsync(d_ws, 0, (size_t)(4 * BATCH * HID) * sizeof(float) + 64, stream);

  hipLaunchKernelGGL(seq2seq_kernel, dim3(NBLK), dim3(NTH), 0, stream, p);
}

// Round 3
// 10043.449 us; speedup vs baseline: 1.8622x; 1.8622x over previous
//
#include <hip/hip_runtime.h>
#include <cmath>

#define NBLK 256
#define NTH  512
#define BATCH 512
#define TENC  256
#define INSZ  32
#define HID   256
#define PREDW 30
#define NTICKS 288

typedef __attribute__((ext_vector_type(4))) float f32x4;
typedef __attribute__((ext_vector_type(8))) short short8;
typedef __attribute__((ext_vector_type(8))) __bf16 bf16x8;

struct SParams {
  const float *input, *target;
  const float *eWih0, *eWhh0, *eBih0, *eBhh0;
  const float *eWih1, *eWhh1, *eBih1, *eBhh1;
  const float *dWih0, *dWhh0, *dBih0, *dBhh0;
  const float *dWih1, *dWhh1, *dBih1, *dBhh1;
  const float *fcw, *fcb;
  float *out;
  char *h0img, *h1img;   // each 1 MiB: [par2][rtile8][hl2][kt8][nt4][1024B]
  unsigned *cnt;
};

__device__ __forceinline__ float sigf(float x) { return 1.0f / (1.0f + expf(-x)); }

__device__ __forceinline__ unsigned short f2bf(float x) {
  unsigned u = __float_as_uint(x);
  u += 0x7fffu + ((u >> 16) & 1u);
  return (unsigned short)(u >> 16);
}
__device__ __forceinline__ float bf2f(unsigned short h) {
  return __uint_as_float(((unsigned)h) << 16);
}

__device__ __forceinline__ void gload_lds16(const void* g, void* l) {
  __builtin_amdgcn_global_load_lds(
      (const __attribute__((address_space(1))) unsigned int*)g,
      (__attribute__((address_space(3))) unsigned int*)l, 16, 0, 0);
}

__device__ __forceinline__ f32x4 mfma16(bf16x8 a, bf16x8 b, f32x4 c) {
  return __builtin_amdgcn_mfma_f32_16x16x32_bf16(a, b, c, 0, 0, 0);
}

__device__ __forceinline__ size_t imgoff(int par, int rt, int hl, int kt, int nt) {
  return (size_t)((((par * 8 + rt) * 2 + hl) * 8 + kt) * 4 + nt) * 1024;
}

__device__ __forceinline__ void grid_sync(unsigned* cnt, unsigned epoch) {
  __syncthreads();
  if (threadIdx.x == 0) {
    __threadfence();   // releases this tick's h-image stores (L2 wb+inv)
    __hip_atomic_fetch_add(cnt, 1u, __ATOMIC_ACQ_REL, __HIP_MEMORY_SCOPE_AGENT);
    const unsigned tgt = (unsigned)NBLK * epoch;
    while (__hip_atomic_load(cnt, __ATOMIC_ACQUIRE, __HIP_MEMORY_SCOPE_AGENT) < tgt) {
      __builtin_amdgcn_s_sleep(2);
    }
    __threadfence();
  }
  __syncthreads();
}

extern __shared__ char smem[];

__global__ __launch_bounds__(NTH) void seq2seq_kernel(SParams p)
{
  const int tid  = threadIdx.x;
  const int bid  = blockIdx.x;
  const int lane = tid & 63;
  const int wid  = tid >> 6;

  // rtile = bid&7 -> all 32 blocks of one rtile land on one XCD (bid%8 rr):
  // h producers and consumers for a row-group share that XCD's L2.
  const int rtile = bid & 7;
  const int role  = bid >> 3;          // 0..31
  const int layer = role >> 4;         // 0,1
  const int dtile = role & 15;
  const int R0 = rtile * 64;
  const int D0 = dtile * 16;

  const int m    = wid >> 1;           // mtile 0..3 (16 gate-cols each)
  const int jj   = wid & 1;            // ntile pair: ntiles {2jj, 2jj+1}
  const int bl15 = lane & 15;
  const int dim_local = m * 4 + (lane >> 4);
  const int dim  = D0 + dim_local;

  // LDS map (dynamic, 155648 B for layer1):
  //  sWih [hl2][m4][KTih][1KB], sWhh [hl2][m4][8][1KB], ring 3x8KB, xbuf 8KB (L0)
  const int KT_ih = layer ? 8 : 1;
  char* sWih = smem;
  char* sWhh = smem + (size_t)2 * 4 * KT_ih * 1024;
  char* ring = sWhh + 65536;
  char* xbuf = ring + 3 * 8192;            // layer0 only
  unsigned* h_img = (unsigned*)ring;       // aliased, used post-ring; [16][65] u32

  // ---- prologue: biases / fc / dec-x weights into regs ----
  const float *bi_e, *bh_e, *bi_d, *bh_d;
  if (layer == 0) { bi_e = p.eBih0; bh_e = p.eBhh0; bi_d = p.dBih0; bh_d = p.dBhh0; }
  else            { bi_e = p.eBih1; bh_e = p.eBhh1; bi_d = p.dBih1; bh_d = p.dBhh1; }
  float be[4], bd[4], wxd[4];
  #pragma unroll
  for (int g = 0; g < 4; ++g) {
    const int grow = g * HID + dim;
    be[g]  = bi_e[grow] + bh_e[grow];
    bd[g]  = bi_d[grow] + bh_d[grow];
    wxd[g] = (layer == 0) ? p.dWih0[grow] : 0.0f;
  }
  const float fcwj = p.fcw[dim];
  const float fcb0 = p.fcb[0];

  // init output to fc bias
  for (int idx = bid * NTH + tid; idx < BATCH * PREDW; idx += NBLK * NTH)
    p.out[idx] = fcb0;

  // ---- prologue: convert encoder weights fp32 -> split-bf16 frag images in LDS ----
  // W M-row r <-> (dim_local=r>>2, gate=r&3); frag slot: lane=(r&15)|((k8&3)<<4)
  auto convW = [&](const float* __restrict__ W, int K, char* dst) {
    const int lg8 = (K == 32) ? 2 : 5;       // log2(K/8)
    const int K8  = 1 << lg8;
    const int KT  = K8 >> 2;
    for (int s = tid; s < 64 * K8; s += NTH) {
      const int r = s >> lg8, k8 = s & (K8 - 1);
      const float* src = W + (size_t)((r & 3) * HID + D0 + (r >> 2)) * K + k8 * 8;
      float4 v0 = *(const float4*)src;
      float4 v1 = *(const float4*)(src + 4);
      float v[8] = {v0.x, v0.y, v0.z, v0.w, v1.x, v1.y, v1.z, v1.w};
      short8 h8, l8;
      #pragma unroll
      for (int q = 0; q < 8; ++q) {
        unsigned short hq = f2bf(v[q]);
        h8[q] = (short)hq;
        l8[q] = (short)f2bf(v[q] - bf2f(hq));
      }
      const int mm = r >> 4, kt = k8 >> 2, li = (r & 15) | ((k8 & 3) << 4);
      *(short8*)(dst + (size_t)((0 * 4 + mm) * KT + kt) * 1024 + li * 16) = h8;
      *(short8*)(dst + (size_t)((1 * 4 + mm) * KT + kt) * 1024 + li * 16) = l8;
    }
  };
  if (layer == 0) { convW(p.eWih0, INSZ, sWih); convW(p.eWhh0, HID, sWhh); }
  else            { convW(p.eWih1, HID, sWih); convW(p.eWhh1, HID, sWhh); }
  __syncthreads();

  float c0 = 0.0f, c1 = 0.0f;     // cell state: (dim, 2 batches) per lane, in regs
  unsigned epoch = 1;

  for (int t = 0; t < NTICKS; ++t) {
    const int rp = t & 1, wp = rp ^ 1;

    bool active = false, isdec = false;
    int s = 0;
    if (layer == 0) {
      if (t < 256)                 { active = true; }
      else if (t >= 257 && t < 287){ active = true; isdec = true; s = t - 257; }
    } else {
      if (t >= 1 && t <= 256)      { active = true; }
      else if (t >= 258)           { active = true; isdec = true; s = t - 258; }
    }
    const int nsteps = layer ? 16 : 8;

    if (active) {
      f32x4 a0, a1;
      #pragma unroll
      for (int q = 0; q < 4; ++q) {
        const float b = isdec ? bd[q] : be[q];
        a0[q] = b; a1[q] = b;
      }

      // L0 encoder: stage x[t] tile as split-bf16 B-frags into xbuf
      if (layer == 0 && !isdec) {
        if (tid < 256) {
          const int b = tid >> 2, k8 = tid & 3;
          const float* src = p.input + (size_t)(R0 + b) * TENC * INSZ + t * INSZ + k8 * 8;
          float4 v0 = *(const float4*)src;
          float4 v1 = *(const float4*)(src + 4);
          float v[8] = {v0.x, v0.y, v0.z, v0.w, v1.x, v1.y, v1.z, v1.w};
          short8 h8, l8;
          #pragma unroll
          for (int q = 0; q < 8; ++q) {
            unsigned short hq = f2bf(v[q]);
            h8[q] = (short)hq;
            l8[q] = (short)f2bf(v[q] - bf2f(hq));
          }
          const int li = (b & 15) | (k8 << 4), nt = b >> 4;
          *(short8*)(xbuf + (size_t)(0 * 4 + nt) * 1024 + li * 16) = h8;
          *(short8*)(xbuf + (size_t)(1 * 4 + nt) * 1024 + li * 16) = l8;
        }
        __syncthreads();
      }

      // ring: issue glds for a (hl,nt) 1KB block per wave per step
      auto ringIssue = [&](int st, int slot) {
        const int hl = wid >> 2, nt = wid & 3;
        int kt; const char* base;
        if (layer == 0) { base = p.h0img; kt = st; }
        else { base = (st >= 8) ? p.h1img : p.h0img; kt = st & 7; }
        const char* g = base + imgoff(rp, rtile, hl, kt, nt) + (size_t)lane * 16;
        gload_lds16(g, ring + (size_t)slot * 8192 + (hl * 4 + nt) * 1024);
      };

      ringIssue(0, 0);
      ringIssue(1, 1);

      // L0 encoder GEMM-A: Wih0 (K=32) x xbuf — overlaps first glds flight
      if (layer == 0 && !isdec) {
        bf16x8 ah = *(const bf16x8*)(sWih + (size_t)(0 * 4 + m) * 1024 + lane * 16);
        bf16x8 al = *(const bf16x8*)(sWih + (size_t)(1 * 4 + m) * 1024 + lane * 16);
        bf16x8 b0h = *(const bf16x8*)(xbuf + (size_t)(0 * 4 + 2 * jj + 0) * 1024 + lane * 16);
        bf16x8 b0l = *(const bf16x8*)(xbuf + (size_t)(1 * 4 + 2 * jj + 0) * 1024 + lane * 16);
        bf16x8 b1h = *(const bf16x8*)(xbuf + (size_t)(0 * 4 + 2 * jj + 1) * 1024 + lane * 16);
        bf16x8 b1l = *(const bf16x8*)(xbuf + (size_t)(1 * 4 + 2 * jj + 1) * 1024 + lane * 16);
        a0 = mfma16(ah, b0h, a0); a0 = mfma16(ah, b0l, a0); a0 = mfma16(al, b0h, a0);
        a1 = mfma16(ah, b1h, a1); a1 = mfma16(ah, b1l, a1); a1 = mfma16(al, b1h, a1);
      }

      // main ring loop: [vmcnt -> s_barrier -> issue(i+2) -> compute(i)]
      for (int i = 0; i < nsteps; ++i) {
        if (i < nsteps - 1) asm volatile("s_waitcnt vmcnt(1)" ::: "memory");
        else                asm volatile("s_waitcnt vmcnt(0)" ::: "memory");
        __builtin_amdgcn_s_barrier();
        asm volatile("" ::: "memory");
        if (i + 2 < nsteps) ringIssue(i + 2, (i + 2) % 3);

        char* wreg; int kt;
        if (layer == 0) { wreg = sWhh; kt = i; }
        else            { wreg = (i < 8) ? sWih : sWhh; kt = i & 7; }
        char* sp = ring + (size_t)(i % 3) * 8192;
        bf16x8 ah = *(const bf16x8*)(wreg + (size_t)((0 * 4 + m) * 8 + kt) * 1024 + lane * 16);
        bf16x8 al = *(const bf16x8*)(wreg + (size_t)((1 * 4 + m) * 8 + kt) * 1024 + lane * 16);
        bf16x8 b0h = *(const bf16x8*)(sp + (size_t)(0 * 4 + 2 * jj + 0) * 1024 + lane * 16);
        bf16x8 b0l = *(const bf16x8*)(sp + (size_t)(1 * 4 + 2 * jj + 0) * 1024 + lane * 16);
        bf16x8 b1h = *(const bf16x8*)(sp + (size_t)(0 * 4 + 2 * jj + 1) * 1024 + lane * 16);
        bf16x8 b1l = *(const bf16x8*)(sp + (size_t)(1 * 4 + 2 * jj + 1) * 1024 + lane * 16);
        a0 = mfma16(ah, b0h, a0); a0 = mfma16(ah, b0l, a0); a0 = mfma16(al, b0h, a0);
        a1 = mfma16(ah, b1h, a1); a1 = mfma16(ah, b1l, a1); a1 = mfma16(al, b1h, a1);
      }
      __syncthreads();   // ring fully consumed; h_img region (alias) now free

      // ---- epilogue: all 4 gates in-lane; c in regs; h -> h_img ----
      #pragma unroll
      for (int nt = 0; nt < 2; ++nt) {
        f32x4 a = nt ? a1 : a0;
        const int bg = R0 + (2 * jj + nt) * 16 + bl15;
        if (isdec && layer == 0) {
          const float xv = p.target[bg * PREDW + s];
          #pragma unroll
          for (int q = 0; q < 4; ++q) a[q] = fmaf(xv, wxd[q], a[q]);
        }
        const float ig = sigf(a[0]);
        const float fg = sigf(a[1]);
        const float gg = tanhf(a[2]);
        const float og = sigf(a[3]);
        float& cr = nt ? c1 : c0;
        cr = fg * cr + ig * gg;
        const float h = og * tanhf(cr);
        if (isdec && layer == 1) {
          float pp = fcwj * h;
          pp += __shfl_xor(pp, 16);
          pp += __shfl_xor(pp, 32);
          if (lane < 16) atomicAdd(p.out + bg * PREDW + s, pp);
        }
        const unsigned hi = f2bf(h);
        const unsigned lo = f2bf(h - bf2f((unsigned short)hi));
        h_img[dim_local * 65 + (2 * jj + nt) * 16 + bl15] = (hi << 16) | lo;
      }
      __syncthreads();

      // assemble 16B chunks and store to the parity-wp global frag image
      if (tid < 256) {
        const int hl = tid >> 7, t2 = tid & 127;
        const int nt = t2 >> 5, lg = (t2 >> 4) & 1, bl = t2 & 15;
        unsigned w[4];
        #pragma unroll
        for (int q = 0; q < 4; ++q) {
          const unsigned v0 = h_img[(lg * 8 + 2 * q) * 65 + nt * 16 + bl];
          const unsigned v1 = h_img[(lg * 8 + 2 * q + 1) * 65 + nt * 16 + bl];
          w[q] = hl ? (((v1 & 0xffffu) << 16) | (v0 & 0xffffu))
                    : ((v1 & 0xffff0000u) | (v0 >> 16));
        }
        const int kg = ((dtile & 1) * 2) + lg, kt = dtile >> 1;
        char* base = layer ? p.h1img : p.h0img;
        uint4 val; val.x = w[0]; val.y = w[1]; val.z = w[2]; val.w = w[3];
        *(uint4*)(base + imgoff(wp, rtile, hl, kt, nt) + (size_t)(bl | (kg << 4)) * 16) = val;
      }
    } else if ((layer == 0 && t == 256) || (layer == 1 && t == 257)) {
      // parity-carry own h slice rp->wp, then swap in decoder weights
      if (tid < 256) {
        const int hl = tid >> 7, t2 = tid & 127;
        const int nt = t2 >> 5, lg = (t2 >> 4) & 1, bl = t2 & 15;
        const int kg = ((dtile & 1) * 2) + lg, kt = dtile >> 1;
        char* base = layer ? p.h1img : p.h0img;
        const size_t sl = (size_t)(bl | (kg << 4)) * 16;
        uint4 v = *(const uint4*)(base + imgoff(rp, rtile, hl, kt, nt) + sl);
        *(uint4*)(base + imgoff(wp, rtile, hl, kt, nt) + sl) = v;
      }
      __syncthreads();
      if (layer == 0) { convW(p.dWhh0, HID, sWhh); }
      else            { convW(p.dWih1, HID, sWih); convW(p.dWhh1, HID, sWhh); }
      __syncthreads();
    }

    grid_sync(p.cnt, epoch);
    ++epoch;
  }
}

extern "C" void kernel_launch(void* const* d_in, const int* in_sizes, int n_in,
                              void* d_out, int out_size, void* d_ws, size_t ws_size,
                              hipStream_t stream)
{
  SParams p;
  p.input = (const float*)d_in[0];
  p.target = (const float*)d_in[1];
  p.eWih0 = (const float*)d_in[2];  p.eWhh0 = (const float*)d_in[3];
  p.eBih0 = (const float*)d_in[4];  p.eBhh0 = (const float*)d_in[5];
  p.eWih1 = (const float*)d_in[6];  p.eWhh1 = (const float*)d_in[7];
  p.eBih1 = (const float*)d_in[8];  p.eBhh1 = (const float*)d_in[9];
  p.dWih0 = (const float*)d_in[10]; p.dWhh0 = (const float*)d_in[11];
  p.dBih0 = (const float*)d_in[12]; p.dBhh0 = (const float*)d_in[13];
  p.dWih1 = (const float*)d_in[14]; p.dWhh1 = (const float*)d_in[15];
  p.dBih1 = (const float*)d_in[16]; p.dBhh1 = (const float*)d_in[17];
  p.fcw = (const float*)d_in[18];   p.fcb = (const float*)d_in[19];
  p.out = (float*)d_out;

  char* ws = (char*)d_ws;
  p.h0img = ws;                        // 1 MiB
  p.h1img = ws + (1 << 20);            // 1 MiB
  p.cnt   = (unsigned*)(ws + (2 << 20));

  // zero h images + barrier counter
  hipMemsetAsync(d_ws, 0, (size_t)(2 << 20) + 64, stream);

  const int shmem = 155648;   // 152 KiB dynamic LDS
  hipFuncSetAttribute((const void*)seq2seq_kernel,
                      hipFuncAttributeMaxDynamicSharedMemorySize, shmem);
  hipLaunchKernelGGL(seq2seq_kernel, dim3(NBLK), dim3(NTH), shmem, stream, p);
}

// Round 5
// 3567.811 us; speedup vs baseline: 5.2423x; 2.8150x over previous
//
#include <hip/hip_runtime.h>
#include <cmath>

#define NBLK 256
#define NTH  512
#define BATCH 512
#define TENC  256
#define INSZ  32
#define HID   256
#define PREDW 30
#define NTICKS 288

typedef __attribute__((ext_vector_type(4))) float f32x4;
typedef __attribute__((ext_vector_type(8))) short short8;
typedef __attribute__((ext_vector_type(8))) __bf16 bf16x8;
typedef __attribute__((ext_vector_type(4))) unsigned int u32x4;

struct SParams {
  const float *input, *target;
  const float *eWih0, *eWhh0, *eBih0, *eBhh0;
  const float *eWih1, *eWhh1, *eBih1, *eBhh1;
  const float *dWih0, *dWhh0, *dBih0, *dBhh0;
  const float *dWih1, *dWhh1, *dBih1, *dBhh1;
  const float *fcw, *fcb;
  float *out;
  char *h0img, *h1img;   // each 1 MiB: [par2][rtile8][hl2][kt8][nt4][1024B]
  unsigned *cnt;
};

__device__ __forceinline__ float sigf(float x) { return 1.0f / (1.0f + expf(-x)); }

__device__ __forceinline__ unsigned short f2bf(float x) {
  unsigned u = __float_as_uint(x);
  u += 0x7fffu + ((u >> 16) & 1u);
  return (unsigned short)(u >> 16);
}
__device__ __forceinline__ float bf2f(unsigned short h) {
  return __uint_as_float(((unsigned)h) << 16);
}

// Device-scope (sc0|sc1 = cpol 17) global->LDS: load bypasses L1/L2, reads LLC.
__device__ __forceinline__ void gload_lds16_sc(const void* g, void* l) {
  __builtin_amdgcn_global_load_lds(
      (const __attribute__((address_space(1))) unsigned int*)g,
      (__attribute__((address_space(3))) unsigned int*)l, 16, 0, 17);
}

// Device-scope store: write-through to LLC (coherence point) — no fence needed.
// NOTE: asm "v" constraints need ext_vector types (HIP uint4 struct fails:
// "indirect register inputs" — R4 compile error).
__device__ __forceinline__ void gstore16_sc(void* gptr, u32x4 v) {
  asm volatile("global_store_dwordx4 %0, %1, off sc0 sc1" :: "v"(gptr), "v"(v) : "memory");
}
__device__ __forceinline__ void gstore4_sc(float* gptr, float v) {
  asm volatile("global_store_dword %0, %1, off sc0 sc1" :: "v"(gptr), "v"(v) : "memory");
}
__device__ __forceinline__ u32x4 gload16_sc(const void* gptr) {
  u32x4 r;
  asm volatile("global_load_dwordx4 %0, %1, off sc0 sc1" : "=v"(r) : "v"(gptr) : "memory");
  asm volatile("s_waitcnt vmcnt(0)" ::: "memory");   // asm load: compiler won't auto-wait
  return r;
}

__device__ __forceinline__ f32x4 mfma16(bf16x8 a, bf16x8 b, f32x4 c) {
  return __builtin_amdgcn_mfma_f32_16x16x32_bf16(a, b, c, 0, 0, 0);
}

__device__ __forceinline__ size_t imgoff(int par, int rt, int hl, int kt, int nt) {
  return (size_t)((((par * 8 + rt) * 2 + hl) * 8 + kt) * 4 + nt) * 1024;
}

// Relaxed grid barrier: all cross-block data moves via sc1 accesses (meets at
// LLC), so NO acquire/release cache maintenance (buffer_wbl2/buffer_inv) is
// needed — that was ~90% of R3's tick time.
__device__ __forceinline__ void grid_sync(unsigned* cnt, unsigned epoch) {
  asm volatile("s_waitcnt vmcnt(0)" ::: "memory");  // sc1 stores reached LLC
  __syncthreads();
  if (threadIdx.x == 0) {
    __hip_atomic_fetch_add(cnt, 1u, __ATOMIC_RELAXED, __HIP_MEMORY_SCOPE_AGENT);
    const unsigned tgt = (unsigned)NBLK * epoch;
    while (__hip_atomic_load(cnt, __ATOMIC_RELAXED, __HIP_MEMORY_SCOPE_AGENT) < tgt) {
      __builtin_amdgcn_s_sleep(1);
    }
  }
  __syncthreads();
  asm volatile("" ::: "memory");
}

extern __shared__ char smem[];

__global__ __launch_bounds__(NTH) void seq2seq_kernel(SParams p)
{
  const int tid  = threadIdx.x;
  const int bid  = blockIdx.x;
  const int lane = tid & 63;
  const int wid  = tid >> 6;

  // rtile = bid&7: h producer/consumer blocks of one row-group cluster on one
  // XCD (perf heuristic only — correctness now flows through LLC sc1 accesses).
  const int rtile = bid & 7;
  const int role  = bid >> 3;          // 0..31
  const int layer = role >> 4;         // 0,1
  const int dtile = role & 15;
  const int R0 = rtile * 64;
  const int D0 = dtile * 16;

  const int m    = wid >> 1;           // mtile 0..3 (16 gate-cols each)
  const int jj   = wid & 1;            // ntile pair: ntiles {2jj, 2jj+1}
  const int bl15 = lane & 15;
  const int dim_local = m * 4 + (lane >> 4);
  const int dim  = D0 + dim_local;

  // LDS map (dynamic, 155648 B for layer1):
  //  sWih [hl2][m4][KTih][1KB], sWhh [hl2][m4][8][1KB], ring 3x8KB, xbuf 8KB (L0)
  const int KT_ih = layer ? 8 : 1;
  char* sWih = smem;
  char* sWhh = smem + (size_t)2 * 4 * KT_ih * 1024;
  char* ring = sWhh + 65536;
  char* xbuf = ring + 3 * 8192;            // layer0 only
  unsigned* h_img = (unsigned*)ring;       // aliased, used post-ring; [16][65] u32

  // ---- prologue: biases / fc / dec-x weights into regs ----
  const float *bi_e, *bh_e, *bi_d, *bh_d;
  if (layer == 0) { bi_e = p.eBih0; bh_e = p.eBhh0; bi_d = p.dBih0; bh_d = p.dBhh0; }
  else            { bi_e = p.eBih1; bh_e = p.eBhh1; bi_d = p.dBih1; bh_d = p.dBhh1; }
  float be[4], bd[4], wxd[4];
  #pragma unroll
  for (int g = 0; g < 4; ++g) {
    const int grow = g * HID + dim;
    be[g]  = bi_e[grow] + bh_e[grow];
    bd[g]  = bi_d[grow] + bh_d[grow];
    wxd[g] = (layer == 0) ? p.dWih0[grow] : 0.0f;
  }
  const float fcwj = p.fcw[dim];
  const float fcb0 = p.fcb[0];

  // init output to fc bias — sc1 stores so later device-scope atomicAdds (which
  // RMW at the LLC) never race a dirty L2 line from this init.
  for (int idx = bid * NTH + tid; idx < BATCH * PREDW; idx += NBLK * NTH)
    gstore4_sc(p.out + idx, fcb0);

  // ---- prologue: convert encoder weights fp32 -> split-bf16 frag images in LDS ----
  // W M-row r <-> (dim_local=r>>2, gate=r&3); frag slot: lane=(r&15)|((k8&3)<<4)
  auto convW = [&](const float* __restrict__ W, int K, char* dst) {
    const int lg8 = (K == 32) ? 2 : 5;       // log2(K/8)
    const int K8  = 1 << lg8;
    const int KT  = K8 >> 2;
    for (int s = tid; s < 64 * K8; s += NTH) {
      const int r = s >> lg8, k8 = s & (K8 - 1);
      const float* src = W + (size_t)((r & 3) * HID + D0 + (r >> 2)) * K + k8 * 8;
      float4 v0 = *(const float4*)src;
      float4 v1 = *(const float4*)(src + 4);
      float v[8] = {v0.x, v0.y, v0.z, v0.w, v1.x, v1.y, v1.z, v1.w};
      short8 h8, l8;
      #pragma unroll
      for (int q = 0; q < 8; ++q) {
        unsigned short hq = f2bf(v[q]);
        h8[q] = (short)hq;
        l8[q] = (short)f2bf(v[q] - bf2f(hq));
      }
      const int mm = r >> 4, kt = k8 >> 2, li = (r & 15) | ((k8 & 3) << 4);
      *(short8*)(dst + (size_t)((0 * 4 + mm) * KT + kt) * 1024 + li * 16) = h8;
      *(short8*)(dst + (size_t)((1 * 4 + mm) * KT + kt) * 1024 + li * 16) = l8;
    }
  };
  if (layer == 0) { convW(p.eWih0, INSZ, sWih); convW(p.eWhh0, HID, sWhh); }
  else            { convW(p.eWih1, HID, sWih); convW(p.eWhh1, HID, sWhh); }
  __syncthreads();

  float c0 = 0.0f, c1 = 0.0f;     // cell state: (dim, 2 batches) per lane, in regs
  unsigned epoch = 1;

  for (int t = 0; t < NTICKS; ++t) {
    const int rp = t & 1, wp = rp ^ 1;

    bool active = false, isdec = false;
    int s = 0;
    if (layer == 0) {
      if (t < 256)                 { active = true; }
      else if (t >= 257 && t < 287){ active = true; isdec = true; s = t - 257; }
    } else {
      if (t >= 1 && t <= 256)      { active = true; }
      else if (t >= 258)           { active = true; isdec = true; s = t - 258; }
    }
    const int nsteps = layer ? 16 : 8;

    if (active) {
      f32x4 a0, a1;
      #pragma unroll
      for (int q = 0; q < 4; ++q) {
        const float b = isdec ? bd[q] : be[q];
        a0[q] = b; a1[q] = b;
      }

      // L0 encoder: stage x[t] tile as split-bf16 B-frags into xbuf
      if (layer == 0 && !isdec) {
        if (tid < 256) {
          const int b = tid >> 2, k8 = tid & 3;
          const float* src = p.input + (size_t)(R0 + b) * TENC * INSZ + t * INSZ + k8 * 8;
          float4 v0 = *(const float4*)src;
          float4 v1 = *(const float4*)(src + 4);
          float v[8] = {v0.x, v0.y, v0.z, v0.w, v1.x, v1.y, v1.z, v1.w};
          short8 h8, l8;
          #pragma unroll
          for (int q = 0; q < 8; ++q) {
            unsigned short hq = f2bf(v[q]);
            h8[q] = (short)hq;
            l8[q] = (short)f2bf(v[q] - bf2f(hq));
          }
          const int li = (b & 15) | (k8 << 4), nt = b >> 4;
          *(short8*)(xbuf + (size_t)(0 * 4 + nt) * 1024 + li * 16) = h8;
          *(short8*)(xbuf + (size_t)(1 * 4 + nt) * 1024 + li * 16) = l8;
        }
        __syncthreads();
      }

      // ring: issue device-scope glds for a (hl,nt) 1KB block per wave per step
      auto ringIssue = [&](int st, int slot) {
        const int hl = wid >> 2, nt = wid & 3;
        int kt; const char* base;
        if (layer == 0) { base = p.h0img; kt = st; }
        else { base = (st >= 8) ? p.h1img : p.h0img; kt = st & 7; }
        const char* g = base + imgoff(rp, rtile, hl, kt, nt) + (size_t)lane * 16;
        gload_lds16_sc(g, ring + (size_t)slot * 8192 + (hl * 4 + nt) * 1024);
      };

      ringIssue(0, 0);
      ringIssue(1, 1);

      // L0 encoder GEMM-A: Wih0 (K=32) x xbuf — overlaps first glds flight
      if (layer == 0 && !isdec) {
        bf16x8 ah = *(const bf16x8*)(sWih + (size_t)(0 * 4 + m) * 1024 + lane * 16);
        bf16x8 al = *(const bf16x8*)(sWih + (size_t)(1 * 4 + m) * 1024 + lane * 16);
        bf16x8 b0h = *(const bf16x8*)(xbuf + (size_t)(0 * 4 + 2 * jj + 0) * 1024 + lane * 16);
        bf16x8 b0l = *(const bf16x8*)(xbuf + (size_t)(1 * 4 + 2 * jj + 0) * 1024 + lane * 16);
        bf16x8 b1h = *(const bf16x8*)(xbuf + (size_t)(0 * 4 + 2 * jj + 1) * 1024 + lane * 16);
        bf16x8 b1l = *(const bf16x8*)(xbuf + (size_t)(1 * 4 + 2 * jj + 1) * 1024 + lane * 16);
        a0 = mfma16(ah, b0h, a0); a0 = mfma16(ah, b0l, a0); a0 = mfma16(al, b0h, a0);
        a1 = mfma16(ah, b1h, a1); a1 = mfma16(ah, b1l, a1); a1 = mfma16(al, b1h, a1);
      }

      // main ring loop: [vmcnt -> s_barrier -> issue(i+2) -> compute(i)]
      for (int i = 0; i < nsteps; ++i) {
        if (i < nsteps - 1) asm volatile("s_waitcnt vmcnt(1)" ::: "memory");
        else                asm volatile("s_waitcnt vmcnt(0)" ::: "memory");
        __builtin_amdgcn_s_barrier();
        asm volatile("" ::: "memory");
        if (i + 2 < nsteps) ringIssue(i + 2, (i + 2) % 3);

        char* wreg; int kt;
        if (layer == 0) { wreg = sWhh; kt = i; }
        else            { wreg = (i < 8) ? sWih : sWhh; kt = i & 7; }
        char* sp = ring + (size_t)(i % 3) * 8192;
        bf16x8 ah = *(const bf16x8*)(wreg + (size_t)((0 * 4 + m) * 8 + kt) * 1024 + lane * 16);
        bf16x8 al = *(const bf16x8*)(wreg + (size_t)((1 * 4 + m) * 8 + kt) * 1024 + lane * 16);
        bf16x8 b0h = *(const bf16x8*)(sp + (size_t)(0 * 4 + 2 * jj + 0) * 1024 + lane * 16);
        bf16x8 b0l = *(const bf16x8*)(sp + (size_t)(1 * 4 + 2 * jj + 0) * 1024 + lane * 16);
        bf16x8 b1h = *(const bf16x8*)(sp + (size_t)(0 * 4 + 2 * jj + 1) * 1024 + lane * 16);
        bf16x8 b1l = *(const bf16x8*)(sp + (size_t)(1 * 4 + 2 * jj + 1) * 1024 + lane * 16);
        a0 = mfma16(ah, b0h, a0); a0 = mfma16(ah, b0l, a0); a0 = mfma16(al, b0h, a0);
        a1 = mfma16(ah, b1h, a1); a1 = mfma16(ah, b1l, a1); a1 = mfma16(al, b1h, a1);
      }
      __syncthreads();   // ring fully consumed; h_img region (alias) now free

      // ---- epilogue: all 4 gates in-lane; c in regs; h -> h_img ----
      #pragma unroll
      for (int nt = 0; nt < 2; ++nt) {
        f32x4 a = nt ? a1 : a0;
        const int bg = R0 + (2 * jj + nt) * 16 + bl15;
        if (isdec && layer == 0) {
          const float xv = p.target[bg * PREDW + s];
          #pragma unroll
          for (int q = 0; q < 4; ++q) a[q] = fmaf(xv, wxd[q], a[q]);
        }
        const float ig = sigf(a[0]);
        const float fg = sigf(a[1]);
        const float gg = tanhf(a[2]);
        const float og = sigf(a[3]);
        float& cr = nt ? c1 : c0;
        cr = fg * cr + ig * gg;
        const float h = og * tanhf(cr);
        if (isdec && layer == 1) {
          float pp = fcwj * h;
          pp += __shfl_xor(pp, 16);
          pp += __shfl_xor(pp, 32);
          if (lane < 16) atomicAdd(p.out + bg * PREDW + s, pp);
        }
        const unsigned hi = f2bf(h);
        const unsigned lo = f2bf(h - bf2f((unsigned short)hi));
        h_img[dim_local * 65 + (2 * jj + nt) * 16 + bl15] = (hi << 16) | lo;
      }
      __syncthreads();

      // assemble 16B chunks and sc1-store to the parity-wp global frag image
      if (tid < 256) {
        const int hl = tid >> 7, t2 = tid & 127;
        const int nt = t2 >> 5, lg = (t2 >> 4) & 1, bl = t2 & 15;
        unsigned w[4];
        #pragma unroll
        for (int q = 0; q < 4; ++q) {
          const unsigned v0 = h_img[(lg * 8 + 2 * q) * 65 + nt * 16 + bl];
          const unsigned v1 = h_img[(lg * 8 + 2 * q + 1) * 65 + nt * 16 + bl];
          w[q] = hl ? (((v1 & 0xffffu) << 16) | (v0 & 0xffffu))
                    : ((v1 & 0xffff0000u) | (v0 >> 16));
        }
        const int kg = ((dtile & 1) * 2) + lg, kt = dtile >> 1;
        char* base = layer ? p.h1img : p.h0img;
        u32x4 val; val.x = w[0]; val.y = w[1]; val.z = w[2]; val.w = w[3];
        gstore16_sc(base + imgoff(wp, rtile, hl, kt, nt) + (size_t)(bl | (kg << 4)) * 16, val);
      }
    } else if ((layer == 0 && t == 256) || (layer == 1 && t == 257)) {
      // parity-carry own h slice rp->wp, then swap in decoder weights
      if (tid < 256) {
        const int hl = tid >> 7, t2 = tid & 127;
        const int nt = t2 >> 5, lg = (t2 >> 4) & 1, bl = t2 & 15;
        const int kg = ((dtile & 1) * 2) + lg, kt = dtile >> 1;
        char* base = layer ? p.h1img : p.h0img;
        const size_t sl = (size_t)(bl | (kg << 4)) * 16;
        u32x4 v = gload16_sc(base + imgoff(rp, rtile, hl, kt, nt) + sl);
        gstore16_sc(base + imgoff(wp, rtile, hl, kt, nt) + sl, v);
      }
      __syncthreads();
      if (layer == 0) { convW(p.dWhh0, HID, sWhh); }
      else            { convW(p.dWih1, HID, sWih); convW(p.dWhh1, HID, sWhh); }
      __syncthreads();
    }

    grid_sync(p.cnt, epoch);
    ++epoch;
  }
}

extern "C" void kernel_launch(void* const* d_in, const int* in_sizes, int n_in,
                              void* d_out, int out_size, void* d_ws, size_t ws_size,
                              hipStream_t stream)
{
  SParams p;
  p.input = (const float*)d_in[0];
  p.target = (const float*)d_in[1];
  p.eWih0 = (const float*)d_in[2];  p.eWhh0 = (const float*)d_in[3];
  p.eBih0 = (const float*)d_in[4];  p.eBhh0 = (const float*)d_in[5];
  p.eWih1 = (const float*)d_in[6];  p.eWhh1 = (const float*)d_in[7];
  p.eBih1 = (const float*)d_in[8];  p.eBhh1 = (const float*)d_in[9];
  p.dWih0 = (const float*)d_in[10]; p.dWhh0 = (const float*)d_in[11];
  p.dBih0 = (const float*)d_in[12]; p.dBhh0 = (const float*)d_in[13];
  p.dWih1 = (const float*)d_in[14]; p.dWhh1 = (const float*)d_in[15];
  p.dBih1 = (const float*)d_in[16]; p.dBhh1 = (const float*)d_in[17];
  p.fcw = (const float*)d_in[18];   p.fcb = (const float*)d_in[19];
  p.out = (float*)d_out;

  char* ws = (char*)d_ws;
  p.h0img = ws;                        // 1 MiB
  p.h1img = ws + (1 << 20);            // 1 MiB
  p.cnt   = (unsigned*)(ws + (2 << 20));

  // zero h images + barrier counter
  (void)hipMemsetAsync(d_ws, 0, (size_t)(2 << 20) + 64, stream);

  const int shmem = 155648;   // 152 KiB dynamic LDS
  (void)hipFuncSetAttribute((const void*)seq2seq_kernel,
                            hipFuncAttributeMaxDynamicSharedMemorySize, shmem);
  hipLaunchKernelGGL(seq2seq_kernel, dim3(NBLK), dim3(NTH), shmem, stream, p);
}

// Round 6
// 2967.683 us; speedup vs baseline: 6.3023x; 1.2022x over previous
//
#include <hip/hip_runtime.h>
#include <cmath>

#define NBLK 256
#define NTH  512
#define BATCH 512
#define TENC  256
#define INSZ  32
#define HID   256
#define PREDW 30
#define NTICKS 288

typedef __attribute__((ext_vector_type(4))) float f32x4;
typedef __attribute__((ext_vector_type(8))) short short8;
typedef __attribute__((ext_vector_type(8))) __bf16 bf16x8;
typedef __attribute__((ext_vector_type(4))) unsigned int u32x4;

struct SParams {
  const float *input, *target;
  const float *eWih0, *eWhh0, *eBih0, *eBhh0;
  const float *eWih1, *eWhh1, *eBih1, *eBhh1;
  const float *dWih0, *dWhh0, *dBih0, *dBhh0;
  const float *dWih1, *dWhh1, *dBih1, *dBhh1;
  const float *fcw, *fcb;
  float *out;
  char *h0img, *h1img;   // each 1 MiB: [par2][rtile8][hl2][kt8][nt4][1024B]
  unsigned *cnt;         // 8 per-rtile counters, 256B apart
};

__device__ __forceinline__ float sigf(float x) { return 1.0f / (1.0f + expf(-x)); }

__device__ __forceinline__ unsigned short f2bf(float x) {
  unsigned u = __float_as_uint(x);
  u += 0x7fffu + ((u >> 16) & 1u);
  return (unsigned short)(u >> 16);
}
__device__ __forceinline__ float bf2f(unsigned short h) {
  return __uint_as_float(((unsigned)h) << 16);
}

// L2-cacheable global->LDS (aux=0). Freshness is guaranteed by the per-tick
// acquire (buffer_inv sc1) in grid_sync, not by per-access sc bits.
__device__ __forceinline__ void gload_lds16(const void* g, void* l) {
  __builtin_amdgcn_global_load_lds(
      (const __attribute__((address_space(1))) unsigned int*)g,
      (__attribute__((address_space(3))) unsigned int*)l, 16, 0, 0);
}

// Device-scope store: write-through to LLC (coherence point) — no wbl2 needed.
__device__ __forceinline__ void gstore16_sc(void* gptr, u32x4 v) {
  asm volatile("global_store_dwordx4 %0, %1, off sc0 sc1" :: "v"(gptr), "v"(v) : "memory");
}
__device__ __forceinline__ void gstore4_sc(float* gptr, float v) {
  asm volatile("global_store_dword %0, %1, off sc0 sc1" :: "v"(gptr), "v"(v) : "memory");
}

__device__ __forceinline__ f32x4 mfma16(bf16x8 a, bf16x8 b, f32x4 c) {
  return __builtin_amdgcn_mfma_f32_16x16x32_bf16(a, b, c, 0, 0, 0);
}

__device__ __forceinline__ size_t imgoff(int par, int rt, int hl, int kt, int nt) {
  return (size_t)((((par * 8 + rt) * 2 + hl) * 8 + kt) * 4 + nt) * 1024;
}

// Per-rtile barrier (32 blocks): relaxed arrival + relaxed spin + ONE acquire
// load at the end (compiler emits a single buffer_inv sc1 = L1+L2 invalidate,
// making remote sc1-stored h visible to subsequent L2-cacheable loads).
__device__ __forceinline__ void grid_sync(unsigned* cnt, unsigned tgt) {
  asm volatile("s_waitcnt vmcnt(0)" ::: "memory");  // own sc1 stores at LLC
  __syncthreads();
  if (threadIdx.x == 0) {
    __hip_atomic_fetch_add(cnt, 1u, __ATOMIC_RELAXED, __HIP_MEMORY_SCOPE_AGENT);
    while (__hip_atomic_load(cnt, __ATOMIC_RELAXED, __HIP_MEMORY_SCOPE_AGENT) < tgt) { }
    (void)__hip_atomic_load(cnt, __ATOMIC_ACQUIRE, __HIP_MEMORY_SCOPE_AGENT);
  }
  __syncthreads();
  asm volatile("" ::: "memory");
}

extern __shared__ char smem[];

__global__ __launch_bounds__(NTH) void seq2seq_kernel(SParams p)
{
  const int tid  = threadIdx.x;
  const int bid  = blockIdx.x;
  const int lane = tid & 63;
  const int wid  = tid >> 6;

  // rtile = bid&7: the 32 blocks of one rtile (its entire private pipeline)
  // cluster on one XCD under round-robin dispatch -> h exchange is L2-local.
  const int rtile = bid & 7;
  const int role  = bid >> 3;          // 0..31
  const int layer = role >> 4;         // 0,1
  const int dtile = role & 15;
  const int R0 = rtile * 64;
  const int D0 = dtile * 16;

  const int m    = wid >> 1;           // mtile 0..3 (16 gate-cols each)
  const int jj   = wid & 1;            // ntile pair: ntiles {2jj, 2jj+1}
  const int bl15 = lane & 15;
  const int dim_local = m * 4 + (lane >> 4);
  const int dim  = D0 + dim_local;

  // LDS map (dynamic, 155648 B for layer1):
  //  sWih [hl2][m4][KTih][1KB], sWhh [hl2][m4][8][1KB], ring 3x8KB, xbuf 8KB (L0)
  const int KT_ih = layer ? 8 : 1;
  char* sWih = smem;
  char* sWhh = smem + (size_t)2 * 4 * KT_ih * 1024;
  char* ring = sWhh + 65536;
  char* xbuf = ring + 3 * 8192;            // layer0 only
  unsigned* h_img = (unsigned*)ring;       // aliased, used post-ring; [16][65] u32

  unsigned* mycnt = p.cnt + rtile * 64;    // 256B apart per rtile

  // ---- prologue: biases / fc / dec-x weights into regs ----
  const float *bi_e, *bh_e, *bi_d, *bh_d;
  if (layer == 0) { bi_e = p.eBih0; bh_e = p.eBhh0; bi_d = p.dBih0; bh_d = p.dBhh0; }
  else            { bi_e = p.eBih1; bh_e = p.eBhh1; bi_d = p.dBih1; bh_d = p.dBhh1; }
  float be[4], bd[4], wxd[4];
  #pragma unroll
  for (int g = 0; g < 4; ++g) {
    const int grow = g * HID + dim;
    be[g]  = bi_e[grow] + bh_e[grow];
    bd[g]  = bi_d[grow] + bh_d[grow];
    wxd[g] = (layer == 0) ? p.dWih0[grow] : 0.0f;
  }
  const float fcwj = p.fcw[dim];
  const float fcb0 = p.fcb[0];

  // init output to fc bias — sc1 stores so later device-scope atomicAdds (which
  // RMW at the LLC) never race a dirty L2 line from this init.
  for (int idx = bid * NTH + tid; idx < BATCH * PREDW; idx += NBLK * NTH)
    gstore4_sc(p.out + idx, fcb0);

  // ---- prologue: convert encoder weights fp32 -> split-bf16 frag images in LDS ----
  // W M-row r <-> (dim_local=r>>2, gate=r&3); frag slot: lane=(r&15)|((k8&3)<<4)
  auto convW = [&](const float* __restrict__ W, int K, char* dst) {
    const int lg8 = (K == 32) ? 2 : 5;       // log2(K/8)
    const int K8  = 1 << lg8;
    const int KT  = K8 >> 2;
    for (int s = tid; s < 64 * K8; s += NTH) {
      const int r = s >> lg8, k8 = s & (K8 - 1);
      const float* src = W + (size_t)((r & 3) * HID + D0 + (r >> 2)) * K + k8 * 8;
      float4 v0 = *(const float4*)src;
      float4 v1 = *(const float4*)(src + 4);
      float v[8] = {v0.x, v0.y, v0.z, v0.w, v1.x, v1.y, v1.z, v1.w};
      short8 h8, l8;
      #pragma unroll
      for (int q = 0; q < 8; ++q) {
        unsigned short hq = f2bf(v[q]);
        h8[q] = (short)hq;
        l8[q] = (short)f2bf(v[q] - bf2f(hq));
      }
      const int mm = r >> 4, kt = k8 >> 2, li = (r & 15) | ((k8 & 3) << 4);
      *(short8*)(dst + (size_t)((0 * 4 + mm) * KT + kt) * 1024 + li * 16) = h8;
      *(short8*)(dst + (size_t)((1 * 4 + mm) * KT + kt) * 1024 + li * 16) = l8;
    }
  };
  if (layer == 0) { convW(p.eWih0, INSZ, sWih); convW(p.eWhh0, HID, sWhh); }
  else            { convW(p.eWih1, HID, sWih); convW(p.eWhh1, HID, sWhh); }
  __syncthreads();

  float c0 = 0.0f, c1 = 0.0f;     // cell state: (dim, 2 batches) per lane, in regs
  unsigned epoch = 1;

  for (int t = 0; t < NTICKS; ++t) {
    const int rp = t & 1, wp = rp ^ 1;

    bool active = false, isdec = false;
    int s = 0;
    if (layer == 0) {
      if (t < 256)                 { active = true; }
      else if (t >= 257 && t < 287){ active = true; isdec = true; s = t - 257; }
    } else {
      if (t >= 1 && t <= 256)      { active = true; }
      else if (t >= 258)           { active = true; isdec = true; s = t - 258; }
    }
    const int nsteps = layer ? 16 : 8;

    if (active) {
      f32x4 a0, a1;
      #pragma unroll
      for (int q = 0; q < 4; ++q) {
        const float b = isdec ? bd[q] : be[q];
        a0[q] = b; a1[q] = b;
      }

      // L0 encoder: stage x[t] tile as split-bf16 B-frags into xbuf
      if (layer == 0 && !isdec) {
        if (tid < 256) {
          const int b = tid >> 2, k8 = tid & 3;
          const float* src = p.input + (size_t)(R0 + b) * TENC * INSZ + t * INSZ + k8 * 8;
          float4 v0 = *(const float4*)src;
          float4 v1 = *(const float4*)(src + 4);
          float v[8] = {v0.x, v0.y, v0.z, v0.w, v1.x, v1.y, v1.z, v1.w};
          short8 h8, l8;
          #pragma unroll
          for (int q = 0; q < 8; ++q) {
            unsigned short hq = f2bf(v[q]);
            h8[q] = (short)hq;
            l8[q] = (short)f2bf(v[q] - bf2f(hq));
          }
          const int li = (b & 15) | (k8 << 4), nt = b >> 4;
          *(short8*)(xbuf + (size_t)(0 * 4 + nt) * 1024 + li * 16) = h8;
          *(short8*)(xbuf + (size_t)(1 * 4 + nt) * 1024 + li * 16) = l8;
        }
        __syncthreads();
      }

      // ring: issue L2-cacheable glds for a (hl,nt) 1KB block per wave per step
      auto ringIssue = [&](int st, int slot) {
        const int hl = wid >> 2, nt = wid & 3;
        int kt; const char* base;
        if (layer == 0) { base = p.h0img; kt = st; }
        else { base = (st >= 8) ? p.h1img : p.h0img; kt = st & 7; }
        const char* g = base + imgoff(rp, rtile, hl, kt, nt) + (size_t)lane * 16;
        gload_lds16(g, ring + (size_t)slot * 8192 + (hl * 4 + nt) * 1024);
      };

      ringIssue(0, 0);
      ringIssue(1, 1);

      // L0 encoder GEMM-A: Wih0 (K=32) x xbuf — overlaps first glds flight
      if (layer == 0 && !isdec) {
        bf16x8 ah = *(const bf16x8*)(sWih + (size_t)(0 * 4 + m) * 1024 + lane * 16);
        bf16x8 al = *(const bf16x8*)(sWih + (size_t)(1 * 4 + m) * 1024 + lane * 16);
        bf16x8 b0h = *(const bf16x8*)(xbuf + (size_t)(0 * 4 + 2 * jj + 0) * 1024 + lane * 16);
        bf16x8 b0l = *(const bf16x8*)(xbuf + (size_t)(1 * 4 + 2 * jj + 0) * 1024 + lane * 16);
        bf16x8 b1h = *(const bf16x8*)(xbuf + (size_t)(0 * 4 + 2 * jj + 1) * 1024 + lane * 16);
        bf16x8 b1l = *(const bf16x8*)(xbuf + (size_t)(1 * 4 + 2 * jj + 1) * 1024 + lane * 16);
        a0 = mfma16(ah, b0h, a0); a0 = mfma16(ah, b0l, a0); a0 = mfma16(al, b0h, a0);
        a1 = mfma16(ah, b1h, a1); a1 = mfma16(ah, b1l, a1); a1 = mfma16(al, b1h, a1);
      }

      // main ring loop: [vmcnt -> s_barrier -> issue(i+2) -> compute(i)]
      for (int i = 0; i < nsteps; ++i) {
        if (i < nsteps - 1) asm volatile("s_waitcnt vmcnt(1)" ::: "memory");
        else                asm volatile("s_waitcnt vmcnt(0)" ::: "memory");
        __builtin_amdgcn_s_barrier();
        asm volatile("" ::: "memory");
        if (i + 2 < nsteps) ringIssue(i + 2, (i + 2) % 3);

        char* wreg; int kt;
        if (layer == 0) { wreg = sWhh; kt = i; }
        else            { wreg = (i < 8) ? sWih : sWhh; kt = i & 7; }
        char* sp = ring + (size_t)(i % 3) * 8192;
        bf16x8 ah = *(const bf16x8*)(wreg + (size_t)((0 * 4 + m) * 8 + kt) * 1024 + lane * 16);
        bf16x8 al = *(const bf16x8*)(wreg + (size_t)((1 * 4 + m) * 8 + kt) * 1024 + lane * 16);
        bf16x8 b0h = *(const bf16x8*)(sp + (size_t)(0 * 4 + 2 * jj + 0) * 1024 + lane * 16);
        bf16x8 b0l = *(const bf16x8*)(sp + (size_t)(1 * 4 + 2 * jj + 0) * 1024 + lane * 16);
        bf16x8 b1h = *(const bf16x8*)(sp + (size_t)(0 * 4 + 2 * jj + 1) * 1024 + lane * 16);
        bf16x8 b1l = *(const bf16x8*)(sp + (size_t)(1 * 4 + 2 * jj + 1) * 1024 + lane * 16);
        a0 = mfma16(ah, b0h, a0); a0 = mfma16(ah, b0l, a0); a0 = mfma16(al, b0h, a0);
        a1 = mfma16(ah, b1h, a1); a1 = mfma16(ah, b1l, a1); a1 = mfma16(al, b1h, a1);
      }
      __syncthreads();   // ring fully consumed; h_img region (alias) now free

      // ---- epilogue: all 4 gates in-lane; c in regs; h -> h_img ----
      #pragma unroll
      for (int nt = 0; nt < 2; ++nt) {
        f32x4 a = nt ? a1 : a0;
        const int bg = R0 + (2 * jj + nt) * 16 + bl15;
        if (isdec && layer == 0) {
          const float xv = p.target[bg * PREDW + s];
          #pragma unroll
          for (int q = 0; q < 4; ++q) a[q] = fmaf(xv, wxd[q], a[q]);
        }
        const float ig = sigf(a[0]);
        const float fg = sigf(a[1]);
        const float gg = tanhf(a[2]);
        const float og = sigf(a[3]);
        float& cr = nt ? c1 : c0;
        cr = fg * cr + ig * gg;
        const float h = og * tanhf(cr);
        if (isdec && layer == 1) {
          float pp = fcwj * h;
          pp += __shfl_xor(pp, 16);
          pp += __shfl_xor(pp, 32);
          if (lane < 16) atomicAdd(p.out + bg * PREDW + s, pp);
        }
        const unsigned hi = f2bf(h);
        const unsigned lo = f2bf(h - bf2f((unsigned short)hi));
        h_img[dim_local * 65 + (2 * jj + nt) * 16 + bl15] = (hi << 16) | lo;
      }
      __syncthreads();

      // assemble 16B chunks and sc1-store to the parity-wp global frag image
      if (tid < 256) {
        const int hl = tid >> 7, t2 = tid & 127;
        const int nt = t2 >> 5, lg = (t2 >> 4) & 1, bl = t2 & 15;
        unsigned w[4];
        #pragma unroll
        for (int q = 0; q < 4; ++q) {
          const unsigned v0 = h_img[(lg * 8 + 2 * q) * 65 + nt * 16 + bl];
          const unsigned v1 = h_img[(lg * 8 + 2 * q + 1) * 65 + nt * 16 + bl];
          w[q] = hl ? (((v1 & 0xffffu) << 16) | (v0 & 0xffffu))
                    : ((v1 & 0xffff0000u) | (v0 >> 16));
        }
        const int kg = ((dtile & 1) * 2) + lg, kt = dtile >> 1;
        char* base = layer ? p.h1img : p.h0img;
        u32x4 val; val.x = w[0]; val.y = w[1]; val.z = w[2]; val.w = w[3];
        gstore16_sc(base + imgoff(wp, rtile, hl, kt, nt) + (size_t)(bl | (kg << 4)) * 16, val);
      }
    } else if ((layer == 0 && t == 256) || (layer == 1 && t == 257)) {
      // parity-carry own h slice rp->wp (own data, fresh post-inv: plain load),
      // then swap in decoder weights
      if (tid < 256) {
        const int hl = tid >> 7, t2 = tid & 127;
        const int nt = t2 >> 5, lg = (t2 >> 4) & 1, bl = t2 & 15;
        const int kg = ((dtile & 1) * 2) + lg, kt = dtile >> 1;
        char* base = layer ? p.h1img : p.h0img;
        const size_t sl = (size_t)(bl | (kg << 4)) * 16;
        u32x4 v = *(const u32x4*)(base + imgoff(rp, rtile, hl, kt, nt) + sl);
        gstore16_sc(base + imgoff(wp, rtile, hl, kt, nt) + sl, v);
      }
      __syncthreads();
      if (layer == 0) { convW(p.dWhh0, HID, sWhh); }
      else            { convW(p.dWih1, HID, sWih); convW(p.dWhh1, HID, sWhh); }
      __syncthreads();
    }

    grid_sync(mycnt, 32u * epoch);
    ++epoch;
  }
}

extern "C" void kernel_launch(void* const* d_in, const int* in_sizes, int n_in,
                              void* d_out, int out_size, void* d_ws, size_t ws_size,
                              hipStream_t stream)
{
  SParams p;
  p.input = (const float*)d_in[0];
  p.target = (const float*)d_in[1];
  p.eWih0 = (const float*)d_in[2];  p.eWhh0 = (const float*)d_in[3];
  p.eBih0 = (const float*)d_in[4];  p.eBhh0 = (const float*)d_in[5];
  p.eWih1 = (const float*)d_in[6];  p.eWhh1 = (const float*)d_in[7];
  p.eBih1 = (const float*)d_in[8];  p.eBhh1 = (const float*)d_in[9];
  p.dWih0 = (const float*)d_in[10]; p.dWhh0 = (const float*)d_in[11];
  p.dBih0 = (const float*)d_in[12]; p.dBhh0 = (const float*)d_in[13];
  p.dWih1 = (const float*)d_in[14]; p.dWhh1 = (const float*)d_in[15];
  p.dBih1 = (const float*)d_in[16]; p.dBhh1 = (const float*)d_in[17];
  p.fcw = (const float*)d_in[18];   p.fcb = (const float*)d_in[19];
  p.out = (float*)d_out;

  char* ws = (char*)d_ws;
  p.h0img = ws;                        // 1 MiB
  p.h1img = ws + (1 << 20);            // 1 MiB
  p.cnt   = (unsigned*)(ws + (2 << 20));  // 8 counters, 256B apart

  // zero h images + barrier counters
  (void)hipMemsetAsync(d_ws, 0, (size_t)(2 << 20) + 2048, stream);

  const int shmem = 155648;   // 152 KiB dynamic LDS
  (void)hipFuncSetAttribute((const void*)seq2seq_kernel,
                            hipFuncAttributeMaxDynamicSharedMemorySize, shmem);
  hipLaunchKernelGGL(seq2seq_kernel, dim3(NBLK), dim3(NTH), shmem, stream, p);
}

// Round 8
// 2755.896 us; speedup vs baseline: 6.7867x; 1.0768x over previous
//
#include <hip/hip_runtime.h>
#include <cmath>

#define NBLK 256
#define NTH  512
#define BATCH 512
#define TENC  256
#define INSZ  32
#define HID   256
#define PREDW 30
#define NTICKS 288

typedef __attribute__((ext_vector_type(4))) float f32x4;
typedef __attribute__((ext_vector_type(8))) short short8;
typedef __attribute__((ext_vector_type(8))) __bf16 bf16x8;
typedef __attribute__((ext_vector_type(4))) unsigned int u32x4;

struct SParams {
  const float *input, *target;
  const float *eWih0, *eWhh0, *eBih0, *eBhh0;
  const float *eWih1, *eWhh1, *eBih1, *eBhh1;
  const float *dWih0, *dWhh0, *dBih0, *dBhh0;
  const float *dWih1, *dWhh1, *dBih1, *dBhh1;
  const float *fcw, *fcb;
  float *out;
  char *h0img, *h1img;   // each 1 MiB: [par2][rtile8][hl2][kt8][nt4][1024B]
  unsigned *cnt;         // 8 per-rtile counters, 256B apart
};

__device__ __forceinline__ float sigf(float x) { return 1.0f / (1.0f + expf(-x)); }

__device__ __forceinline__ unsigned short f2bf(float x) {
  unsigned u = __float_as_uint(x);
  u += 0x7fffu + ((u >> 16) & 1u);
  return (unsigned short)(u >> 16);
}
__device__ __forceinline__ float bf2f(unsigned short h) {
  return __uint_as_float(((unsigned)h) << 16);
}

// Device-scope (sc0|sc1 = cpol 17) global->LDS: reads LLC directly (R5-proven
// correct for cross-XCD h exchange; no inv needed anywhere).
__device__ __forceinline__ void gload_lds16_sc(const void* g, void* l) {
  __builtin_amdgcn_global_load_lds(
      (const __attribute__((address_space(1))) unsigned int*)g,
      (__attribute__((address_space(3))) unsigned int*)l, 16, 0, 17);
}

// Device-scope store: write-through to LLC (coherence point).
__device__ __forceinline__ void gstore16_sc(void* gptr, u32x4 v) {
  asm volatile("global_store_dwordx4 %0, %1, off sc0 sc1" :: "v"(gptr), "v"(v) : "memory");
}
__device__ __forceinline__ void gstore4_sc(float* gptr, float v) {
  asm volatile("global_store_dword %0, %1, off sc0 sc1" :: "v"(gptr), "v"(v) : "memory");
}

__device__ __forceinline__ f32x4 mfma16(bf16x8 a, bf16x8 b, f32x4 c) {
  return __builtin_amdgcn_mfma_f32_16x16x32_bf16(a, b, c, 0, 0, 0);
}

__device__ __forceinline__ size_t imgoff(int par, int rt, int hl, int kt, int nt) {
  return (size_t)((((par * 8 + rt) * 2 + hl) * 8 + kt) * 4 + nt) * 1024;
}

// Counted waits; k is compile-time after full unroll (switch folds).
__device__ __forceinline__ void wait_vmcnt_k(int k) {
  switch (k) {
    case 0: asm volatile("s_waitcnt vmcnt(0)" ::: "memory"); break;
    case 1: asm volatile("s_waitcnt vmcnt(1)" ::: "memory"); break;
    case 2: asm volatile("s_waitcnt vmcnt(2)" ::: "memory"); break;
    case 3: asm volatile("s_waitcnt vmcnt(3)" ::: "memory"); break;
    case 4: asm volatile("s_waitcnt vmcnt(4)" ::: "memory"); break;
    default: asm volatile("s_waitcnt vmcnt(5)" ::: "memory"); break;
  }
}

// Pure-relaxed per-rtile barrier (32 blocks). All cross-block data moves via
// sc0sc1 accesses meeting at the LLC -> no acquire/release cache maintenance.
__device__ __forceinline__ void grid_sync(unsigned* cnt, unsigned tgt) {
  asm volatile("s_waitcnt vmcnt(0)" ::: "memory");  // own sc1 stores at LLC
  __syncthreads();
  if (threadIdx.x == 0) {
    __hip_atomic_fetch_add(cnt, 1u, __ATOMIC_RELAXED, __HIP_MEMORY_SCOPE_AGENT);
    while (__hip_atomic_load(cnt, __ATOMIC_RELAXED, __HIP_MEMORY_SCOPE_AGENT) < tgt) { }
  }
  __syncthreads();
  asm volatile("" ::: "memory");
}

extern __shared__ char smem[];

__global__ __launch_bounds__(NTH, 2) void seq2seq_kernel(SParams p)
{
  const int tid  = threadIdx.x;
  const int bid  = blockIdx.x;
  const int lane = tid & 63;
  const int wid  = tid >> 6;

  // rtile = bid&7: one rtile's private pipeline clusters on one XCD under
  // round-robin dispatch (perf heuristic only; correctness is LLC-mediated).
  const int rtile = bid & 7;
  const int role  = bid >> 3;          // 0..31
  const int layer = role >> 4;         // 0,1
  const int dtile = role & 15;
  const int R0 = rtile * 64;
  const int D0 = dtile * 16;

  const int m    = wid >> 1;           // mtile 0..3
  const int jj   = wid & 1;            // ntile pair {2jj, 2jj+1}
  const int bl15 = lane & 15;
  const int k8l  = lane >> 4;          // 0..3
  const int dim_local = m * 4 + (lane >> 4);
  const int dim  = D0 + dim_local;

  // LDS: ring 8 x 8KB (h staging) + xbuf 8KB (L0 enc). Weights live in VGPRs.
  char* ring = smem;
  char* xbuf = smem + 8 * 8192;
  unsigned* h_img = (unsigned*)smem;   // alias ring slot0 (post-loop use only)

  unsigned* mycnt = p.cnt + rtile * 64;

  // ---- biases / fc / dec-x weights into regs ----
  const float *bi_e, *bh_e, *bi_d, *bh_d;
  if (layer == 0) { bi_e = p.eBih0; bh_e = p.eBhh0; bi_d = p.dBih0; bh_d = p.dBhh0; }
  else            { bi_e = p.eBih1; bh_e = p.eBhh1; bi_d = p.dBih1; bh_d = p.dBhh1; }
  float be[4], bd[4], wxd[4];
  #pragma unroll
  for (int g = 0; g < 4; ++g) {
    const int grow = g * HID + dim;
    be[g]  = bi_e[grow] + bh_e[grow];
    bd[g]  = bi_d[grow] + bh_d[grow];
    wxd[g] = (layer == 0) ? p.dWih0[grow] : 0.0f;
  }
  const float fcwj = p.fcw[dim];
  const float fcb0 = p.fcb[0];

  // init output to fc bias (sc1 so LLC atomicAdds never race a dirty L2 line)
  for (int idx = bid * NTH + tid; idx < BATCH * PREDW; idx += NBLK * NTH)
    gstore4_sc(p.out + idx, fcb0);

  // ---- weights fp32 -> split-bf16 A-frags, directly into REGISTERS ----
  // A-frag lane (r&15)|((k8&3)<<4), r = m*16 + (lane&15): row/gate derivation
  // identical to the LDS convW that validated at absmax 6.1e-5.
  const int wrow = (bl15 & 3) * HID + D0 + m * 4 + (bl15 >> 2);
  auto convReg = [&](const float* __restrict__ W, int K, int kt, bf16x8& hf, bf16x8& lf) {
    const float* src = W + (size_t)wrow * K + (size_t)(kt * 4 + k8l) * 8;
    float4 v0 = *(const float4*)src;
    float4 v1 = *(const float4*)(src + 4);
    float v[8] = {v0.x, v0.y, v0.z, v0.w, v1.x, v1.y, v1.z, v1.w};
    short8 hs, ls;
    #pragma unroll
    for (int e = 0; e < 8; ++e) {
      unsigned short hq = f2bf(v[e]);
      hs[e] = (short)hq;
      ls[e] = (short)f2bf(v[e] - bf2f(hq));
    }
    hf = __builtin_bit_cast(bf16x8, hs);
    lf = __builtin_bit_cast(bf16x8, ls);
  };

  bf16x8 wh[16], wl[16];   // statically indexed only (rule #20)
  if (layer == 0) {
    convReg(p.eWih0, INSZ, 0, wh[0], wl[0]);
    #pragma unroll
    for (int kt = 0; kt < 8; ++kt) convReg(p.eWhh0, HID, kt, wh[1 + kt], wl[1 + kt]);
  } else {
    #pragma unroll
    for (int kt = 0; kt < 8; ++kt) convReg(p.eWih1, HID, kt, wh[kt], wl[kt]);
    #pragma unroll
    for (int kt = 0; kt < 8; ++kt) convReg(p.eWhh1, HID, kt, wh[8 + kt], wl[8 + kt]);
  }

  float c0 = 0.0f, c1 = 0.0f;
  unsigned epoch = 1;

  for (int t = 0; t < NTICKS; ++t) {
    const int rp = t & 1, wp = rp ^ 1;

    bool active = false, isdec = false;
    int s = 0;
    if (layer == 0) {
      if (t < 256)                 { active = true; }
      else if (t >= 257 && t < 287){ active = true; isdec = true; s = t - 257; }
    } else {
      if (t >= 1 && t <= 256)      { active = true; }
      else if (t >= 258)           { active = true; isdec = true; s = t - 258; }
    }

    if (active) {
      f32x4 a0, a1;
      #pragma unroll
      for (int q = 0; q < 4; ++q) {
        const float b = isdec ? bd[q] : be[q];
        a0[q] = b; a1[q] = b;
      }

      auto ringIssue = [&](int st, int slot) {
        const int hl = wid >> 2, nt = wid & 3;
        const char* base; int kt;
        if (layer == 0) { base = p.h0img; kt = st; }
        else { base = (st >= 8) ? p.h1img : p.h0img; kt = st & 7; }
        const char* g = base + imgoff(rp, rtile, hl, kt, nt) + (size_t)lane * 16;
        gload_lds16_sc(g, ring + (size_t)slot * 8192 + (hl * 4 + nt) * 1024);
      };

      // L0 enc: stage x[t] FIRST (its compiler-inserted vmcnt(0) must not
      // drain the ring prefetches issued below)
      if (layer == 0 && !isdec) {
        if (tid < 256) {
          const int b = tid >> 2, k8 = tid & 3;
          const float* src = p.input + (size_t)(R0 + b) * TENC * INSZ + t * INSZ + k8 * 8;
          float4 v0 = *(const float4*)src;
          float4 v1 = *(const float4*)(src + 4);
          float v[8] = {v0.x, v0.y, v0.z, v0.w, v1.x, v1.y, v1.z, v1.w};
          short8 h8, l8;
          #pragma unroll
          for (int q = 0; q < 8; ++q) {
            unsigned short hq = f2bf(v[q]);
            h8[q] = (short)hq;
            l8[q] = (short)f2bf(v[q] - bf2f(hq));
          }
          const int li = (b & 15) | (k8 << 4), nt = b >> 4;
          *(short8*)(xbuf + (size_t)(0 * 4 + nt) * 1024 + li * 16) = h8;
          *(short8*)(xbuf + (size_t)(1 * 4 + nt) * 1024 + li * 16) = l8;
        }
      }

      // 6-deep ring prologue
      #pragma unroll
      for (int st = 0; st < 6; ++st) ringIssue(st, st);

      // L0 enc GEMM-A (Wih0 x xbuf) overlaps the prefetch flight
      if (layer == 0 && !isdec) {
        __syncthreads();
        bf16x8 b0h = *(const bf16x8*)(xbuf + (size_t)(0 + 2 * jj + 0) * 1024 + lane * 16);
        bf16x8 b0l = *(const bf16x8*)(xbuf + (size_t)(4 + 2 * jj + 0) * 1024 + lane * 16);
        bf16x8 b1h = *(const bf16x8*)(xbuf + (size_t)(0 + 2 * jj + 1) * 1024 + lane * 16);
        bf16x8 b1l = *(const bf16x8*)(xbuf + (size_t)(4 + 2 * jj + 1) * 1024 + lane * 16);
        a0 = mfma16(wh[0], b0h, a0); a0 = mfma16(wh[0], b0l, a0); a0 = mfma16(wl[0], b0h, a0);
        a1 = mfma16(wh[0], b1h, a1); a1 = mfma16(wh[0], b1l, a1); a1 = mfma16(wl[0], b1h, a1);
      }

      // main ring loop: counted vmcnt -> barrier -> issue(i+6) -> 6 MFMA.
      // Weights come from registers; only h B-frags touch LDS.
      auto ringStep = [&](int i, int NS, bf16x8 ah, bf16x8 al) {
        const int kk = NS - 1 - i;
        wait_vmcnt_k(kk < 5 ? kk : 5);
        __builtin_amdgcn_s_barrier();
        asm volatile("" ::: "memory");
        if (i + 6 < NS) ringIssue(i + 6, (i + 6) & 7);
        char* sp = ring + (size_t)(i & 7) * 8192;
        bf16x8 b0h = *(const bf16x8*)(sp + (size_t)(0 + 2 * jj + 0) * 1024 + lane * 16);
        bf16x8 b0l = *(const bf16x8*)(sp + (size_t)(4 + 2 * jj + 0) * 1024 + lane * 16);
        bf16x8 b1h = *(const bf16x8*)(sp + (size_t)(0 + 2 * jj + 1) * 1024 + lane * 16);
        bf16x8 b1l = *(const bf16x8*)(sp + (size_t)(4 + 2 * jj + 1) * 1024 + lane * 16);
        a0 = mfma16(ah, b0h, a0); a0 = mfma16(ah, b0l, a0); a0 = mfma16(al, b0h, a0);
        a1 = mfma16(ah, b1h, a1); a1 = mfma16(ah, b1l, a1); a1 = mfma16(al, b1h, a1);
      };
      if (layer == 0) {
        #pragma unroll
        for (int i = 0; i < 8; ++i) ringStep(i, 8, wh[1 + i], wl[1 + i]);
      } else {
        #pragma unroll
        for (int i = 0; i < 16; ++i) ringStep(i, 16, wh[i], wl[i]);
      }
      __syncthreads();   // ring drained; h_img alias region now free

      // ---- epilogue: gates in-lane; c in regs; h -> h_img ----
      #pragma unroll
      for (int nt = 0; nt < 2; ++nt) {
        f32x4 a = nt ? a1 : a0;
        const int bg = R0 + (2 * jj + nt) * 16 + bl15;
        if (isdec && layer == 0) {
          const float xv = p.target[bg * PREDW + s];
          #pragma unroll
          for (int q = 0; q < 4; ++q) a[q] = fmaf(xv, wxd[q], a[q]);
        }
        const float ig = sigf(a[0]);
        const float fg = sigf(a[1]);
        const float gg = tanhf(a[2]);
        const float og = sigf(a[3]);
        float& cr = nt ? c1 : c0;
        cr = fg * cr + ig * gg;
        const float h = og * tanhf(cr);
        if (isdec && layer == 1) {
          float pp = fcwj * h;
          pp += __shfl_xor(pp, 16);
          pp += __shfl_xor(pp, 32);
          if (lane < 16) atomicAdd(p.out + bg * PREDW + s, pp);
        }
        const unsigned hi = f2bf(h);
        const unsigned lo = f2bf(h - bf2f((unsigned short)hi));
        h_img[dim_local * 65 + (2 * jj + nt) * 16 + bl15] = (hi << 16) | lo;
      }
      __syncthreads();

      // assemble 16B chunks and sc1-store to the parity-wp global frag image
      if (tid < 256) {
        const int hl = tid >> 7, t2 = tid & 127;
        const int nt = t2 >> 5, lg = (t2 >> 4) & 1, bl = t2 & 15;
        unsigned w[4];
        #pragma unroll
        for (int q = 0; q < 4; ++q) {
          const unsigned v0 = h_img[(lg * 8 + 2 * q) * 65 + nt * 16 + bl];
          const unsigned v1 = h_img[(lg * 8 + 2 * q + 1) * 65 + nt * 16 + bl];
          w[q] = hl ? (((v1 & 0xffffu) << 16) | (v0 & 0xffffu))
                    : ((v1 & 0xffff0000u) | (v0 >> 16));
        }
        const int kg = ((dtile & 1) * 2) + lg, kt = dtile >> 1;
        char* base = layer ? p.h1img : p.h0img;
        u32x4 val; val.x = w[0]; val.y = w[1]; val.z = w[2]; val.w = w[3];
        gstore16_sc(base + imgoff(wp, rtile, hl, kt, nt) + (size_t)(bl | (kg << 4)) * 16, val);
      }
    } else if ((layer == 0 && t == 256) || (layer == 1 && t == 257)) {
      // parity-carry own h slice rp->wp (own data: plain load is safe — the
      // only prior accesses to this line are this block's own sc stores),
      // then swap decoder weights into regs
      if (tid < 256) {
        const int hl = tid >> 7, t2 = tid & 127;
        const int nt = t2 >> 5, lg = (t2 >> 4) & 1, bl = t2 & 15;
        const int kg = ((dtile & 1) * 2) + lg, kt = dtile >> 1;
        char* base = layer ? p.h1img : p.h0img;
        const size_t sl = (size_t)(bl | (kg << 4)) * 16;
        u32x4 v = *(const u32x4*)(base + imgoff(rp, rtile, hl, kt, nt) + sl);
        gstore16_sc(base + imgoff(wp, rtile, hl, kt, nt) + sl, v);
      }
      if (layer == 0) {
        #pragma unroll
        for (int kt = 0; kt < 8; ++kt) convReg(p.dWhh0, HID, kt, wh[1 + kt], wl[1 + kt]);
      } else {
        #pragma unroll
        for (int kt = 0; kt < 8; ++kt) convReg(p.dWih1, HID, kt, wh[kt], wl[kt]);
        #pragma unroll
        for (int kt = 0; kt < 8; ++kt) convReg(p.dWhh1, HID, kt, wh[8 + kt], wl[8 + kt]);
      }
    }

    grid_sync(mycnt, 32u * epoch);
    ++epoch;
  }
}

extern "C" void kernel_launch(void* const* d_in, const int* in_sizes, int n_in,
                              void* d_out, int out_size, void* d_ws, size_t ws_size,
                              hipStream_t stream)
{
  SParams p;
  p.input = (const float*)d_in[0];
  p.target = (const float*)d_in[1];
  p.eWih0 = (const float*)d_in[2];  p.eWhh0 = (const float*)d_in[3];
  p.eBih0 = (const float*)d_in[4];  p.eBhh0 = (const float*)d_in[5];
  p.eWih1 = (const float*)d_in[6];  p.eWhh1 = (const float*)d_in[7];
  p.eBih1 = (const float*)d_in[8];  p.eBhh1 = (const float*)d_in[9];
  p.dWih0 = (const float*)d_in[10]; p.dWhh0 = (const float*)d_in[11];
  p.dBih0 = (const float*)d_in[12]; p.dBhh0 = (const float*)d_in[13];
  p.dWih1 = (const float*)d_in[14]; p.dWhh1 = (const float*)d_in[15];
  p.dBih1 = (const float*)d_in[16]; p.dBhh1 = (const float*)d_in[17];
  p.fcw = (const float*)d_in[18];   p.fcb = (const float*)d_in[19];
  p.out = (float*)d_out;

  char* ws = (char*)d_ws;
  p.h0img = ws;                        // 1 MiB
  p.h1img = ws + (1 << 20);            // 1 MiB
  p.cnt   = (unsigned*)(ws + (2 << 20));  // 8 counters, 256B apart

  (void)hipMemsetAsync(d_ws, 0, (size_t)(2 << 20) + 2048, stream);

  const int shmem = 8 * 8192 + 8192;   // 72 KiB: ring + xbuf
  (void)hipFuncSetAttribute((const void*)seq2seq_kernel,
                            hipFuncAttributeMaxDynamicSharedMemorySize, shmem);
  hipLaunchKernelGGL(seq2seq_kernel, dim3(NBLK), dim3(NTH), shmem, stream, p);
}